// Round 16
// baseline (176.141 us; speedup 1.0000x reference)
//
#include <hip/hip_runtime.h>

#define BB 128
#define TT 2048
#define II 32
#define HH 64

typedef __attribute__((ext_vector_type(8))) short bf16x8;
typedef __attribute__((ext_vector_type(4))) float f32x4;

__device__ __forceinline__ unsigned f2bf(float f) {
    unsigned u = __builtin_bit_cast(unsigned, f);
    return (u + 0x7fffu + ((u >> 16) & 1u)) >> 16;   // RNE truncation to bf16
}

// Packed RNE f32->bf16 pair (R12-verified bit-identical to f2bf).
__device__ __forceinline__ unsigned cvtpk(float lo, float hi) {
    unsigned r;
    asm("v_cvt_pk_bf16_f32 %0, %1, %2" : "=v"(r) : "v"(lo), "v"(hi));
    return r;
}

// Swizzled float-index into xwsh[16][512] (one t-quarter).
// Bank audit: C-store instr -> bank = (l&15) | ((wv&1 ^ (l>>4)&1)<<4): every
// bank exactly 2 lanes = free (m136).  Snapshot f4 read -> bank bits 2-4 =
// k ^ (l&7): 8 banks x 2 lanes = free.  Bijective per row (XOR bits 2-5 from
// t bits 5-8 + row-const bit 4; all < 512).
__device__ __forceinline__ int swzQ(int r, int t) {
    return (((r << 9) + t) ^ (((t >> 5) & 15) << 2)) ^ (((r >> 2) & 1) << 4);
}

// ---- scan sequence macros over locals q0..q7 (time order / reversed) -------
#define FWD_SEQ(M) \
  M(q0.x) M(q0.y) M(q0.z) M(q0.w) M(q1.x) M(q1.y) M(q1.z) M(q1.w) \
  M(q2.x) M(q2.y) M(q2.z) M(q2.w) M(q3.x) M(q3.y) M(q3.z) M(q3.w) \
  M(q4.x) M(q4.y) M(q4.z) M(q4.w) M(q5.x) M(q5.y) M(q5.z) M(q5.w) \
  M(q6.x) M(q6.y) M(q6.z) M(q6.w) M(q7.x) M(q7.y) M(q7.z) M(q7.w)
#define BWD_SEQ(M) \
  M(q7.w) M(q7.z) M(q7.y) M(q7.x) M(q6.w) M(q6.z) M(q6.y) M(q6.x) \
  M(q5.w) M(q5.z) M(q5.y) M(q5.x) M(q4.w) M(q4.z) M(q4.y) M(q4.x) \
  M(q3.w) M(q3.z) M(q3.y) M(q3.x) M(q2.w) M(q2.z) M(q2.y) M(q2.x) \
  M(q1.w) M(q1.z) M(q1.y) M(q1.x) M(q0.w) M(q0.z) M(q0.y) M(q0.x)

// ---- general-W fallback: serial chain, one wave per (dir,b) ----------------
template<int DIR>
__device__ __noinline__ void rnn_serial_f(
    const float* __restrict__ Wih, const float* __restrict__ bih,
    const float* __restrict__ bhh, const float* __restrict__ Whh,
    const float* __restrict__ x, unsigned short* __restrict__ hbuf,
    int b, int lane, float (*hs)[HH])
{
    const float bias = bih[lane] + bhh[lane];
    const float4* wip = (const float4*)(Wih + lane * II);
    const float4* whp = (const float4*)(Whh + lane * HH);
    hs[0][lane] = 0.0f;
    unsigned short* hb = hbuf + ((size_t)(DIR * BB + b) * HH + lane) * TT;
    int cur = 0;
    for (int s = 0; s < TT; ++s) {
        const int t = DIR ? (TT - 1 - s) : s;
        const float4* xr = (const float4*)(x + ((size_t)b * TT + t) * II);
        float a0 = bias, a1 = 0.f, a2 = 0.f, a3 = 0.f;
        #pragma unroll
        for (int i4 = 0; i4 < II / 4; ++i4) {
            const float4 w4 = wip[i4];
            const float4 v  = xr[i4];
            a0 = fmaf(w4.x, v.x, a0); a1 = fmaf(w4.y, v.y, a1);
            a2 = fmaf(w4.z, v.z, a2); a3 = fmaf(w4.w, v.w, a3);
        }
        float s0 = 0.f, s1 = 0.f, s2 = 0.f, s3 = 0.f;
        const float* hc = hs[cur];
        #pragma unroll
        for (int j4 = 0; j4 < HH / 4; ++j4) {
            const float4 w4 = whp[j4];
            const float4 h4 = *(const float4*)(hc + 4 * j4);
            s0 = fmaf(w4.x, h4.x, s0); s1 = fmaf(w4.y, h4.y, s1);
            s2 = fmaf(w4.z, h4.z, s2); s3 = fmaf(w4.w, h4.w, s3);
        }
        const float h = fmaxf((a0 + a1) + (a2 + a3) + ((s0 + s1) + (s2 + s3)), 0.0f);
        hs[cur ^ 1][lane] = h;
        hb[t] = (unsigned short)f2bf(h);
        cur ^= 1;
    }
}

// ---- fused proj+rnn v6: dual-direction blocks (every MFMA row real) --------
// R13-R15: rnn pinned at ~67 us against conflict/occupancy/barrier/latency
// edits -> attack total work.  Block owns 8 rows of EACH dir: A-frag rows
// 0-7 = Wf, 8-15 = Wb (16/16 real, was 8/16).  Grid 2048 -> 1024: total
// staging and MFMA count HALVE.  xwsh = [16][512] quarter-buffer; scans
// snapshot per quarter (lane group l>>4 == qq; lane still owns t [32l,32l+32)
// -> bit-exact).  Each wave scans 2 rows (dir0 + dir1) -- grid-total scan
// work conserved.  All arithmetic bit-identical -> absmax 2.384186e-07.
__global__ __launch_bounds__(512, 4) void rnn_fused_kernel(
    const float* __restrict__ x,
    const float* __restrict__ Wf, const float* __restrict__ bihf, const float* __restrict__ bhhf,
    const float* __restrict__ Wb, const float* __restrict__ bihb, const float* __restrict__ bhhb,
    const float* __restrict__ Whf, const float* __restrict__ Whb,
    unsigned short* __restrict__ hbuf)
{
    __shared__ __align__(16) float xwsh[16 * 512];              // 32 KB (t-quarter)
    __shared__ __align__(16) unsigned short xst[2][8][512];     // 16 KB wave-private stage
    __shared__ float sflags[2];
    __shared__ __align__(16) float hshd[2][2][HH];              // 2 KB fallback

    const int tid  = threadIdx.x;
    const int lane = tid & 63;
    const int wv   = __builtin_amdgcn_readfirstlane(tid >> 6);  // 0..7
    const int blk  = blockIdx.x;                                // 0..1023
    const int xcd  = blk & 7;
    const int rank = blk >> 3;                                  // 0..127
    const int b    = ((rank >> 3) << 3) | xcd;
    const int g8   = (rank & 7) << 3;                           // row base (per dir)

    // ---- W_hh == I check (waves 0/1), flags to LDS ----
    if (wv < 2) {
        const float* W = wv ? Whb : Whf;
        bool ok = true;
        const float4* wp = (const float4*)(W + lane * HH);
        #pragma unroll
        for (int j4 = 0; j4 < HH / 4; ++j4) {
            float4 v = wp[j4];
            ok &= (v.x == ((4*j4+0 == lane) ? 1.0f : 0.0f));
            ok &= (v.y == ((4*j4+1 == lane) ? 1.0f : 0.0f));
            ok &= (v.z == ((4*j4+2 == lane) ? 1.0f : 0.0f));
            ok &= (v.w == ((4*j4+3 == lane) ? 1.0f : 0.0f));
        }
        const bool isI = (__ballot(ok) == ~0ull);
        if (lane == 0) sflags[wv] = isI ? 1.0f : 0.0f;
    }
    __syncthreads();
    const bool iF = sflags[0] != 0.0f;
    const bool iB = sflags[1] != 0.0f;

    if (iF | iB) {
        // ---- A-fragment: 16 REAL rows (0-7 = Wf g8+m, 8-15 = Wb g8+m-8) ----
        bf16x8 afrag;
        {
            const int m = lane & 15, kg = lane >> 4;
            const float* Wrow = ((m < 8) ? (Wf + (g8 + m) * II)
                                         : (Wb + (g8 + m - 8) * II)) + kg * 8;
            const float4 wa = *(const float4*)Wrow;
            const float4 wc = *(const float4*)(Wrow + 4);
            uint4 ap;
            ap.x = cvtpk(wa.x, wa.y);
            ap.y = cvtpk(wa.z, wa.w);
            ap.z = cvtpk(wc.x, wc.y);
            ap.w = cvtpk(wc.z, wc.w);
            afrag = __builtin_bit_cast(bf16x8, ap);
        }
        // ---- bias C-init (C row mc = (lane>>4)*4 + j; 0-7 f, 8-15 b) ----
        f32x4 cbias;
        {
            const int r0 = lane >> 4;
            #pragma unroll
            for (int j = 0; j < 4; ++j) {
                const int mc = r0 * 4 + j;
                cbias[j] = (mc < 8) ? (bihf[g8 + mc] + bhhf[g8 + mc])
                                    : (bihb[g8 + mc - 8] + bhhb[g8 + mc - 8]);
            }
        }

        // wave-private stage (R14-verified): lane's 2 f4s -> bf16 units.
        #define STAGE(BUFI, V0, V1) {                                           \
            unsigned short* bp_ = xst[BUFI][wv];                                \
            const int base_ = ((lane >> 3) << 5) + ((lane & 7) << 2);           \
            uint2 p_;                                                           \
            p_.x = cvtpk(V0.x, V0.y);                                           \
            p_.y = cvtpk(V0.z, V0.w);                                           \
            *(uint2*)(bp_ + base_) = p_;                                        \
            p_.x = cvtpk(V1.x, V1.y);                                           \
            p_.y = cvtpk(V1.z, V1.w);                                           \
            *(uint2*)(bp_ + base_ + 256) = p_;                                  \
        }

        float4 qA0 = {0,0,0,0}, qA1 = {0,0,0,0}, qA2 = {0,0,0,0}, qA3 = {0,0,0,0},
               qA4 = {0,0,0,0}, qA5 = {0,0,0,0}, qA6 = {0,0,0,0}, qA7 = {0,0,0,0};
        float4 qB0 = {0,0,0,0}, qB1 = {0,0,0,0}, qB2 = {0,0,0,0}, qB3 = {0,0,0,0},
               qB4 = {0,0,0,0}, qB5 = {0,0,0,0}, qB6 = {0,0,0,0}, qB7 = {0,0,0,0};

        #define SNAPQ(QQ) {                                                     \
            if ((lane >> 4) == (QQ)) {                                          \
                const int tb = (lane & 15) << 5;                                \
                qA0 = *(const float4*)(xwsh + swzQ(wv, tb + 0));                \
                qA1 = *(const float4*)(xwsh + swzQ(wv, tb + 4));                \
                qA2 = *(const float4*)(xwsh + swzQ(wv, tb + 8));                \
                qA3 = *(const float4*)(xwsh + swzQ(wv, tb + 12));               \
                qA4 = *(const float4*)(xwsh + swzQ(wv, tb + 16));               \
                qA5 = *(const float4*)(xwsh + swzQ(wv, tb + 20));               \
                qA6 = *(const float4*)(xwsh + swzQ(wv, tb + 24));               \
                qA7 = *(const float4*)(xwsh + swzQ(wv, tb + 28));               \
                qB0 = *(const float4*)(xwsh + swzQ(8 + wv, tb + 0));            \
                qB1 = *(const float4*)(xwsh + swzQ(8 + wv, tb + 4));            \
                qB2 = *(const float4*)(xwsh + swzQ(8 + wv, tb + 8));            \
                qB3 = *(const float4*)(xwsh + swzQ(8 + wv, tb + 12));           \
                qB4 = *(const float4*)(xwsh + swzQ(8 + wv, tb + 16));           \
                qB5 = *(const float4*)(xwsh + swzQ(8 + wv, tb + 20));           \
                qB6 = *(const float4*)(xwsh + swzQ(8 + wv, tb + 24));           \
                qB7 = *(const float4*)(xwsh + swzQ(8 + wv, tb + 28));           \
            }                                                                   \
        }

        // wave's f4 slab base for chunk cc: xb4 + cc*1024 + wv*128
        const float4* xb4 = (const float4*)(x + (size_t)b * TT * II) + (wv << 7);
        // prologue: stage chunk 0; chunks 1 (va) and 2 (vb) in regs
        {
            const float4 a0 = xb4[lane], a1 = xb4[lane + 64];
            STAGE(0, a0, a1)
        }
        float4 va0 = xb4[1024 + lane], va1 = xb4[1024 + lane + 64];
        float4 vb0 = xb4[2048 + lane], vb1 = xb4[2048 + lane + 64];

        #pragma unroll
        for (int cc = 0; cc < 16; ++cc) {
            if (cc == 4 || cc == 8 || cc == 12) {   // quarter boundary
                __syncthreads();
                SNAPQ((cc >> 2) - 1)
                __syncthreads();                    // snapshot before overwrite
            }
            // bfrag ds_read first (buffer written >= 1 iter ago)
            const bf16x8 bfrag = *(const bf16x8*)(xst[cc & 1][wv] +
                ((lane & 15) << 5) + ((lane >> 4) << 3));
            // issue loads for chunk cc+3 (3-deep)
            float4 na0, na1;
            if (cc < 13) {
                const float4* gp = xb4 + ((cc + 3) << 10);
                na0 = gp[lane]; na1 = gp[lane + 64];
            }
            // stage chunk cc+1 (wave-private, no barrier)
            if (cc < 15) { STAGE((cc + 1) & 1, va0, va1) }
            // MFMA + C-store: ALL 16 rows real, all 64 lanes store
            {
                f32x4 accv = __builtin_amdgcn_mfma_f32_16x16x32_bf16(afrag, bfrag, cbias, 0, 0, 0);
                const int th = ((cc & 3) << 7) + (wv << 4) + (lane & 15);
                const int m0 = (lane >> 4) << 2;
                xwsh[swzQ(m0 + 0, th)] = accv[0];
                xwsh[swzQ(m0 + 1, th)] = accv[1];
                xwsh[swzQ(m0 + 2, th)] = accv[2];
                xwsh[swzQ(m0 + 3, th)] = accv[3];
            }
            va0 = vb0; va1 = vb1;
            vb0 = na0; vb1 = na1;
        }
        #undef STAGE

        // ---- final quarter snapshot ----
        __syncthreads();
        SNAPQ(3)
        #undef SNAPQ

        const int hrow = g8 + wv;

        // ---- scan row A (dir 0), bit-exact R2 path ----
        if (iF) {
            float4 q0 = qA0, q1 = qA1, q2 = qA2, q3 = qA3,
                   q4 = qA4, q5 = qA5, q6 = qA6, q7 = qA7;
            float A = 0.0f, Bv = -__builtin_inff();
            #define CSTEP(c) { A = A + (c); Bv = fmaxf(Bv + (c), 0.0f); }
            FWD_SEQ(CSTEP)
            #undef CSTEP
            #pragma unroll
            for (int off = 1; off < 64; off <<= 1) {
                float Au = __shfl_up(A,  (unsigned)off);
                float Bu = __shfl_up(Bv, (unsigned)off);
                if (lane >= off) {
                    Bv = fmaxf(Bu + A, Bv);
                    A  = Au + A;
                }
            }
            float Ae = __shfl_up(A, 1u);
            float Be = __shfl_up(Bv, 1u);
            float h = (lane == 0) ? 0.0f : fmaxf(Ae, Be);
            #define ASTEP(c) { h = fmaxf(h + (c), 0.0f); (c) = h; }
            FWD_SEQ(ASTEP)
            #undef ASTEP
            unsigned short* hb = hbuf + ((size_t)b * HH + hrow) * TT + (lane << 5);
            uint4 s0q, s1q, s2q, s3q;
            s0q.x = cvtpk(q0.x, q0.y); s0q.y = cvtpk(q0.z, q0.w);
            s0q.z = cvtpk(q1.x, q1.y); s0q.w = cvtpk(q1.z, q1.w);
            s1q.x = cvtpk(q2.x, q2.y); s1q.y = cvtpk(q2.z, q2.w);
            s1q.z = cvtpk(q3.x, q3.y); s1q.w = cvtpk(q3.z, q3.w);
            s2q.x = cvtpk(q4.x, q4.y); s2q.y = cvtpk(q4.z, q4.w);
            s2q.z = cvtpk(q5.x, q5.y); s2q.w = cvtpk(q5.z, q5.w);
            s3q.x = cvtpk(q6.x, q6.y); s3q.y = cvtpk(q6.z, q6.w);
            s3q.z = cvtpk(q7.x, q7.y); s3q.w = cvtpk(q7.z, q7.w);
            uint4* hv = (uint4*)hb;
            hv[0] = s0q; hv[1] = s1q; hv[2] = s2q; hv[3] = s3q;
        }

        // ---- scan row B (dir 1), bit-exact R2 path ----
        if (iB) {
            float4 q0 = qB0, q1 = qB1, q2 = qB2, q3 = qB3,
                   q4 = qB4, q5 = qB5, q6 = qB6, q7 = qB7;
            float A = 0.0f, Bv = -__builtin_inff();
            #define CSTEP(c) { A = A + (c); Bv = fmaxf(Bv + (c), 0.0f); }
            BWD_SEQ(CSTEP)
            #undef CSTEP
            #pragma unroll
            for (int off = 1; off < 64; off <<= 1) {
                float Au = __shfl_down(A,  (unsigned)off);
                float Bu = __shfl_down(Bv, (unsigned)off);
                if (lane < 64 - off) {
                    Bv = fmaxf(Bu + A, Bv);
                    A  = Au + A;
                }
            }
            float Ae = __shfl_down(A, 1u);
            float Be = __shfl_down(Bv, 1u);
            float h = (lane == 63) ? 0.0f : fmaxf(Ae, Be);
            #define ASTEP(c) { h = fmaxf(h + (c), 0.0f); (c) = h; }
            BWD_SEQ(ASTEP)
            #undef ASTEP
            unsigned short* hb = hbuf + ((size_t)(BB + b) * HH + hrow) * TT + (lane << 5);
            uint4 s0q, s1q, s2q, s3q;
            s0q.x = cvtpk(q0.x, q0.y); s0q.y = cvtpk(q0.z, q0.w);
            s0q.z = cvtpk(q1.x, q1.y); s0q.w = cvtpk(q1.z, q1.w);
            s1q.x = cvtpk(q2.x, q2.y); s1q.y = cvtpk(q2.z, q2.w);
            s1q.z = cvtpk(q3.x, q3.y); s1q.w = cvtpk(q3.z, q3.w);
            s2q.x = cvtpk(q4.x, q4.y); s2q.y = cvtpk(q4.z, q4.w);
            s2q.z = cvtpk(q5.x, q5.y); s2q.w = cvtpk(q5.z, q5.w);
            s3q.x = cvtpk(q6.x, q6.y); s3q.y = cvtpk(q6.z, q6.w);
            s3q.z = cvtpk(q7.x, q7.y); s3q.w = cvtpk(q7.z, q7.w);
            uint4* hv = (uint4*)hb;
            hv[0] = s0q; hv[1] = s1q; hv[2] = s2q; hv[3] = s3q;
        }
    }

    // ---- non-identity fallback (one serial wave per dir, rank&7 == 0) ----
    if (!iF && (rank & 7) == 0 && wv == 0)
        rnn_serial_f<0>(Wf, bihf, bhhf, Whf, x, hbuf, b, lane, hshd[0]);
    if (!iB && (rank & 7) == 0 && wv == 1)
        rnn_serial_f<1>(Wb, bihb, bhhb, Whb, x, hbuf, b, lane, hshd[1]);
}

// ---------------- mlp: R12 exact (coalesced w0 + cvt_pk) --------------------
__global__ __launch_bounds__(256) void mlp_kernel(
    const unsigned short* __restrict__ hbuf,
    const float* __restrict__ w0, const float* __restrict__ b0,
    const float* __restrict__ w1, const float* __restrict__ b1,
    float* __restrict__ out)
{
    const int tid  = threadIdx.x;
    const int lane = tid & 63;
    const int wv   = tid >> 6;            // 0..3
    const int blk  = blockIdx.x;          // 0..4095
    const int b    = blk >> 5;
    const int t0   = (blk & 31) << 6;     // 64 t per block

    __shared__ __align__(16) unsigned int w0dw[128 * 64];   // 32 KB
    __shared__ __align__(16) unsigned int hsh[128 * 32];    // 16 KB

    // ---- stage w0: dense coalesced f4 loads, swizzled-linear LDS image ----
    #pragma unroll
    for (int it = 0; it < 16; ++it) {
        const int q = it * 256 + tid;         // f4 index 0..4095 (dense)
        const float4 v = ((const float4*)w0)[q];
        uint2 p;
        p.x = cvtpk(v.x, v.y);
        p.y = cvtpk(v.z, v.w);
        const int k  = q >> 5;                // k row 0..127
        const int dw = (k << 6) + ((q & 31) << 1);
        *(uint2*)(w0dw + (dw ^ ((k & 15) << 2))) = p;
    }

    // ---- stage h tile: 4 coalesced uint4 per thread ----
    #pragma unroll
    for (int it = 0; it < 4; ++it) {
        const int q   = it * 256 + tid;
        const int j   = q >> 3, sub = q & 7;
        const unsigned short* rp =
            hbuf + ((size_t)((j >> 6) * BB + b) * HH + (j & 63)) * TT + t0;
        const uint4 v = *(const uint4*)(rp + sub * 8);
        const int dwb = j * 32 + sub * 4;
        *(uint4*)(hsh + (dwb ^ (((j >> 3) & 3) << 3))) = v;
    }
    __syncthreads();

    const int lg = lane >> 4;                      // k-group 0..3
    const int tl = (wv << 4) + (lane & 15);        // t within tile
    const int t  = t0 + tl;                        // output column
    const int m  = lane & 15;

    f32x4 acc[8];
    #pragma unroll
    for (int kt = 0; kt < 8; ++kt) {
        const float4 v = *(const float4*)(b0 + kt * 16 + lg * 4);
        acc[kt][0] = v.x; acc[kt][1] = v.y; acc[kt][2] = v.z; acc[kt][3] = v.w;
    }

    const unsigned short* hus = (const unsigned short*)hsh;
    #pragma unroll
    for (int jt = 0; jt < 4; ++jt) {
        bf16x8 bf;
        #pragma unroll
        for (int i = 0; i < 8; ++i) {
            const int j  = jt * 32 + lg * 8 + i;
            const int dw = (j * 32 + (tl >> 1)) ^ (lg << 3);
            bf[i] = (short)hus[dw * 2 + (tl & 1)];
        }
        #pragma unroll
        for (int kt = 0; kt < 8; ++kt) {
            const int krow = kt * 16 + m;
            const bf16x8 af = *(const bf16x8*)(w0dw +
                ((((krow << 6) + (jt << 4) + (lg << 2)) ^ ((krow & 15) << 2))));
            acc[kt] = __builtin_amdgcn_mfma_f32_16x16x32_bf16(af, bf, acc[kt], 0, 0, 0);
        }
    }

    float o = 0.0f;
    #pragma unroll
    for (int kt = 0; kt < 8; ++kt) {
        const float4 wq = *(const float4*)(w1 + kt * 16 + lg * 4);
        float v0 = acc[kt][0]; v0 = fmaxf(v0, 0.01f * v0); o = fmaf(v0, wq.x, o);
        float v1 = acc[kt][1]; v1 = fmaxf(v1, 0.01f * v1); o = fmaf(v1, wq.y, o);
        float v2 = acc[kt][2]; v2 = fmaxf(v2, 0.01f * v2); o = fmaf(v2, wq.z, o);
        float v3 = acc[kt][3]; v3 = fmaxf(v3, 0.01f * v3); o = fmaf(v3, wq.w, o);
    }
    o += __shfl_xor(o, 16);
    o += __shfl_xor(o, 32);
    if (lg == 0) out[(size_t)b * TT + t] = o + b1[0];
}

extern "C" void kernel_launch(void* const* d_in, const int* in_sizes, int n_in,
                              void* d_out, int out_size, void* d_ws, size_t ws_size,
                              hipStream_t stream) {
    (void)in_sizes; (void)n_in; (void)out_size; (void)ws_size;
    const float* x    = (const float*)d_in[0];
    const float* Wihf = (const float*)d_in[1];
    const float* Whhf = (const float*)d_in[2];
    const float* bihf = (const float*)d_in[3];
    const float* bhhf = (const float*)d_in[4];
    const float* Wihb = (const float*)d_in[5];
    const float* Whhb = (const float*)d_in[6];
    const float* bihb = (const float*)d_in[7];
    const float* bhhb = (const float*)d_in[8];
    const float* ff0w = (const float*)d_in[9];
    const float* ff0b = (const float*)d_in[10];
    const float* ff1w = (const float*)d_in[11];
    const float* ff1b = (const float*)d_in[12];
    unsigned short* hbuf = (unsigned short*)d_ws;   // [2][BB][HH][TT] bf16, 67 MB

    rnn_fused_kernel<<<dim3(8 * BB), dim3(512), 0, stream>>>(
        x, Wihf, bihf, bhhf, Wihb, bihb, bhhb, Whhf, Whhb, hbuf);
    mlp_kernel<<<dim3(BB * (TT / 64)), dim3(256), 0, stream>>>(
        hbuf, ff0w, ff0b, ff1w, ff1b, (float*)d_out);
}

// Round 17
// 168.753 us; speedup vs baseline: 1.0438x; 1.0438x over previous
//
#include <hip/hip_runtime.h>

#define BB 128
#define TT 2048
#define II 32
#define HH 64

typedef __attribute__((ext_vector_type(8))) short bf16x8;
typedef __attribute__((ext_vector_type(4))) float f32x4;

__device__ __forceinline__ unsigned f2bf(float f) {
    unsigned u = __builtin_bit_cast(unsigned, f);
    return (u + 0x7fffu + ((u >> 16) & 1u)) >> 16;   // RNE truncation to bf16
}

// Packed RNE f32->bf16 pair (R12-verified bit-identical to f2bf).
__device__ __forceinline__ unsigned cvtpk(float lo, float hi) {
    unsigned r;
    asm("v_cvt_pk_bf16_f32 %0, %1, %2" : "=v"(r) : "v"(lo), "v"(hi));
    return r;
}

// Swizzled float-index into xwsh[8][1024] (R10-verified conflict-free store).
__device__ __forceinline__ int swzW(int r, int t) {
    return (((r << 10) + t) ^ (((t >> 5) & 31) << 2)) ^ ((r & 7) << 2);
}

// ---- scan sequence macros over locals q0..q7 (time order / reversed) -------
#define FWD_SEQ(M) \
  M(q0.x) M(q0.y) M(q0.z) M(q0.w) M(q1.x) M(q1.y) M(q1.z) M(q1.w) \
  M(q2.x) M(q2.y) M(q2.z) M(q2.w) M(q3.x) M(q3.y) M(q3.z) M(q3.w) \
  M(q4.x) M(q4.y) M(q4.z) M(q4.w) M(q5.x) M(q5.y) M(q5.z) M(q5.w) \
  M(q6.x) M(q6.y) M(q6.z) M(q6.w) M(q7.x) M(q7.y) M(q7.z) M(q7.w)
#define BWD_SEQ(M) \
  M(q7.w) M(q7.z) M(q7.y) M(q7.x) M(q6.w) M(q6.z) M(q6.y) M(q6.x) \
  M(q5.w) M(q5.z) M(q5.y) M(q5.x) M(q4.w) M(q4.z) M(q4.y) M(q4.x) \
  M(q3.w) M(q3.z) M(q3.y) M(q3.x) M(q2.w) M(q2.z) M(q2.y) M(q2.x) \
  M(q1.w) M(q1.z) M(q1.y) M(q1.x) M(q0.w) M(q0.z) M(q0.y) M(q0.x)

// ---- general-W fallback: serial chain, one wave per (dir,b) ----------------
template<int DIR>
__device__ __noinline__ void rnn_serial_f(
    const float* __restrict__ Wih, const float* __restrict__ bih,
    const float* __restrict__ bhh, const float* __restrict__ Whh,
    const float* __restrict__ x, unsigned short* __restrict__ hbuf,
    int b, int lane, float (*hs)[HH])
{
    const float bias = bih[lane] + bhh[lane];
    const float4* wip = (const float4*)(Wih + lane * II);
    const float4* whp = (const float4*)(Whh + lane * HH);
    hs[0][lane] = 0.0f;
    unsigned short* hb = hbuf + ((size_t)(DIR * BB + b) * HH + lane) * TT;
    int cur = 0;
    for (int s = 0; s < TT; ++s) {
        const int t = DIR ? (TT - 1 - s) : s;
        const float4* xr = (const float4*)(x + ((size_t)b * TT + t) * II);
        float a0 = bias, a1 = 0.f, a2 = 0.f, a3 = 0.f;
        #pragma unroll
        for (int i4 = 0; i4 < II / 4; ++i4) {
            const float4 w4 = wip[i4];
            const float4 v  = xr[i4];
            a0 = fmaf(w4.x, v.x, a0); a1 = fmaf(w4.y, v.y, a1);
            a2 = fmaf(w4.z, v.z, a2); a3 = fmaf(w4.w, v.w, a3);
        }
        float s0 = 0.f, s1 = 0.f, s2 = 0.f, s3 = 0.f;
        const float* hc = hs[cur];
        #pragma unroll
        for (int j4 = 0; j4 < HH / 4; ++j4) {
            const float4 w4 = whp[j4];
            const float4 h4 = *(const float4*)(hc + 4 * j4);
            s0 = fmaf(w4.x, h4.x, s0); s1 = fmaf(w4.y, h4.y, s1);
            s2 = fmaf(w4.z, h4.z, s2); s3 = fmaf(w4.w, h4.w, s3);
        }
        const float h = fmaxf((a0 + a1) + (a2 + a3) + ((s0 + s1) + (s2 + s3)), 0.0f);
        hs[cur ^ 1][lane] = h;
        hb[t] = (unsigned short)f2bf(h);
        cur ^= 1;
    }
}

// ---- fused proj+rnn, MFMA phase-1 v5 (R15 EXACT — best measured: 169.0) ----
__global__ __launch_bounds__(512, 4) void rnn_fused_kernel(
    const float* __restrict__ x,
    const float* __restrict__ Wf, const float* __restrict__ bihf, const float* __restrict__ bhhf,
    const float* __restrict__ Wb, const float* __restrict__ bihb, const float* __restrict__ bhhb,
    const float* __restrict__ Whf, const float* __restrict__ Whb,
    unsigned short* __restrict__ hbuf)
{
    __shared__ __align__(16) float xwsh[8 * 1024];              // 32 KB (t-half)
    __shared__ __align__(16) unsigned short xst[2][8][512];     // 16 KB wave-private stage
    __shared__ float sflags[2];
    __shared__ __align__(16) float hshd[2][2][HH];              // 2 KB fallback

    const int tid  = threadIdx.x;
    const int lane = tid & 63;
    const int wv   = __builtin_amdgcn_readfirstlane(tid >> 6);  // 0..7
    const int blk  = blockIdx.x;
    const int xcd  = blk & 7;
    const int rank = blk >> 3;
    const int b    = ((rank >> 4) << 3) | xcd;
    const int g    = rank & 15;
    const int g4   = g << 2;

    // ---- W_hh == I check (waves 0/1), flags to LDS ----
    if (wv < 2) {
        const float* W = wv ? Whb : Whf;
        bool ok = true;
        const float4* wp = (const float4*)(W + lane * HH);
        #pragma unroll
        for (int j4 = 0; j4 < HH / 4; ++j4) {
            float4 v = wp[j4];
            ok &= (v.x == ((4*j4+0 == lane) ? 1.0f : 0.0f));
            ok &= (v.y == ((4*j4+1 == lane) ? 1.0f : 0.0f));
            ok &= (v.z == ((4*j4+2 == lane) ? 1.0f : 0.0f));
            ok &= (v.w == ((4*j4+3 == lane) ? 1.0f : 0.0f));
        }
        const bool isI = (__ballot(ok) == ~0ull);
        if (lane == 0) sflags[wv] = isI ? 1.0f : 0.0f;
    }
    __syncthreads();
    const bool iF = sflags[0] != 0.0f;
    const bool iB = sflags[1] != 0.0f;

    if (iF | iB) {
        // ---- A-fragment: rows 0-7 = W (bf16), rows 8-15 = 0 ----
        bf16x8 afrag;
        {
            const int m = lane & 15, kg = lane >> 4;
            uint4 ap = {0u, 0u, 0u, 0u};
            if (m < 8) {
                const float* Wrow = ((m < 4) ? (Wf + (g4 + m) * II)
                                             : (Wb + (g4 + m - 4) * II)) + kg * 8;
                const float4 wa = *(const float4*)Wrow;
                const float4 wc = *(const float4*)(Wrow + 4);
                ap.x = cvtpk(wa.x, wa.y);
                ap.y = cvtpk(wa.z, wa.w);
                ap.z = cvtpk(wc.x, wc.y);
                ap.w = cvtpk(wc.z, wc.w);
            }
            afrag = __builtin_bit_cast(bf16x8, ap);
        }
        // ---- bias C-init (C row m = (lane>>4)*4 + j) ----
        f32x4 cbias;
        {
            const int r0 = lane >> 4;
            #pragma unroll
            for (int j = 0; j < 4; ++j) {
                const int m = r0 * 4 + j;
                float v = 0.0f;
                if (m < 4)      v = bihf[g4 + m] + bhhf[g4 + m];
                else if (m < 8) v = bihb[g4 + m - 4] + bhhb[g4 + m - 4];
                cbias[j] = v;
            }
        }

        // wave-private stage (R14-verified): lane's 2 f4s -> bf16 units.
        #define STAGE(BUFI, V0, V1) {                                           \
            unsigned short* bp_ = xst[BUFI][wv];                                \
            const int base_ = ((lane >> 3) << 5) + ((lane & 7) << 2);           \
            uint2 p_;                                                           \
            p_.x = cvtpk(V0.x, V0.y);                                           \
            p_.y = cvtpk(V0.z, V0.w);                                           \
            *(uint2*)(bp_ + base_) = p_;                                        \
            p_.x = cvtpk(V1.x, V1.y);                                           \
            p_.y = cvtpk(V1.z, V1.w);                                           \
            *(uint2*)(bp_ + base_ + 256) = p_;                                  \
        }

        float4 q0 = {0,0,0,0}, q1 = {0,0,0,0}, q2 = {0,0,0,0}, q3 = {0,0,0,0},
               q4 = {0,0,0,0}, q5 = {0,0,0,0}, q6 = {0,0,0,0}, q7 = {0,0,0,0};

        // wave's f4 slab base for chunk cc: xb4 + cc*1024 + wv*128
        const float4* xb4 = (const float4*)(x + (size_t)b * TT * II) + (wv << 7);
        // prologue: stage chunk 0; chunks 1 (va) and 2 (vb) in regs
        {
            const float4 a0 = xb4[lane], a1 = xb4[lane + 64];
            STAGE(0, a0, a1)
        }
        float4 va0 = xb4[1024 + lane], va1 = xb4[1024 + lane + 64];
        float4 vb0 = xb4[2048 + lane], vb1 = xb4[2048 + lane + 64];

        #pragma unroll
        for (int cc = 0; cc < 16; ++cc) {
            if (cc == 8) {   // half-0 xwsh complete across all waves
                __syncthreads();
                if ((lane >> 5) == 0) {
                    const int tb = (lane & 31) << 5;
                    q0 = *(const float4*)(xwsh + swzW(wv, tb + 0));
                    q1 = *(const float4*)(xwsh + swzW(wv, tb + 4));
                    q2 = *(const float4*)(xwsh + swzW(wv, tb + 8));
                    q3 = *(const float4*)(xwsh + swzW(wv, tb + 12));
                    q4 = *(const float4*)(xwsh + swzW(wv, tb + 16));
                    q5 = *(const float4*)(xwsh + swzW(wv, tb + 20));
                    q6 = *(const float4*)(xwsh + swzW(wv, tb + 24));
                    q7 = *(const float4*)(xwsh + swzW(wv, tb + 28));
                }
                __syncthreads();           // snapshot reads before half-1 stores
            }
            // (1) bfrag ds_read FIRST (buffer written >= 1 iter ago)
            const bf16x8 bfrag = *(const bf16x8*)(xst[cc & 1][wv] +
                ((lane & 15) << 5) + ((lane >> 4) << 3));
            // (2) issue loads for chunk cc+3 (3-deep)
            float4 na0, na1;
            if (cc < 13) {
                const float4* gp = xb4 + ((cc + 3) << 10);
                na0 = gp[lane]; na1 = gp[lane + 64];
            }
            // (3) stage chunk cc+1 into the wave's other buffer (no barrier)
            if (cc < 15) { STAGE((cc + 1) & 1, va0, va1) }
            // (4) MFMA + xwsh store
            {
                f32x4 accv = __builtin_amdgcn_mfma_f32_16x16x32_bf16(afrag, bfrag, cbias, 0, 0, 0);
                if (lane < 32) {           // C rows 0..7 only
                    const int th = ((cc & 7) << 7) + (wv << 4) + (lane & 15);
                    const int m0 = (lane >> 4) << 2;
                    xwsh[swzW(m0 + 0, th)] = accv[0];
                    xwsh[swzW(m0 + 1, th)] = accv[1];
                    xwsh[swzW(m0 + 2, th)] = accv[2];
                    xwsh[swzW(m0 + 3, th)] = accv[3];
                }
            }
            va0 = vb0; va1 = vb1;
            vb0 = na0; vb1 = na1;
        }
        #undef STAGE

        // ---- snapshot half 1 ----
        __syncthreads();
        if ((lane >> 5) == 1) {
            const int tb = (lane & 31) << 5;
            q0 = *(const float4*)(xwsh + swzW(wv, tb + 0));
            q1 = *(const float4*)(xwsh + swzW(wv, tb + 4));
            q2 = *(const float4*)(xwsh + swzW(wv, tb + 8));
            q3 = *(const float4*)(xwsh + swzW(wv, tb + 12));
            q4 = *(const float4*)(xwsh + swzW(wv, tb + 16));
            q5 = *(const float4*)(xwsh + swzW(wv, tb + 20));
            q6 = *(const float4*)(xwsh + swzW(wv, tb + 24));
            q7 = *(const float4*)(xwsh + swzW(wv, tb + 28));
        }

        // ---- phase 2: scan (R5/R2-verified, bit-exact) ----
        const int dir  = wv >> 2;
        const int hrow = g4 + (wv & 3);
        const bool en  = dir ? iB : iF;
        if (en) {
            float A = 0.0f, Bv = -__builtin_inff();
            #define CSTEP(c) { A = A + (c); Bv = fmaxf(Bv + (c), 0.0f); }
            if (dir == 0) { FWD_SEQ(CSTEP) } else { BWD_SEQ(CSTEP) }
            #undef CSTEP

            float h;
            if (dir == 0) {
                #pragma unroll
                for (int off = 1; off < 64; off <<= 1) {
                    float Au = __shfl_up(A,  (unsigned)off);
                    float Bu = __shfl_up(Bv, (unsigned)off);
                    if (lane >= off) {
                        Bv = fmaxf(Bu + A, Bv);
                        A  = Au + A;
                    }
                }
                float Ae = __shfl_up(A, 1u);
                float Be = __shfl_up(Bv, 1u);
                h = (lane == 0) ? 0.0f : fmaxf(Ae, Be);
            } else {
                #pragma unroll
                for (int off = 1; off < 64; off <<= 1) {
                    float Au = __shfl_down(A,  (unsigned)off);
                    float Bu = __shfl_down(Bv, (unsigned)off);
                    if (lane < 64 - off) {
                        Bv = fmaxf(Bu + A, Bv);
                        A  = Au + A;
                    }
                }
                float Ae = __shfl_down(A, 1u);
                float Be = __shfl_down(Bv, 1u);
                h = (lane == 63) ? 0.0f : fmaxf(Ae, Be);
            }

            #define ASTEP(c) { h = fmaxf(h + (c), 0.0f); (c) = h; }
            if (dir == 0) { FWD_SEQ(ASTEP) } else { BWD_SEQ(ASTEP) }
            #undef ASTEP

            unsigned short* hb = hbuf + ((size_t)(dir * BB + b) * HH + hrow) * TT + (lane << 5);
            uint4 s0q, s1q, s2q, s3q;
            s0q.x = cvtpk(q0.x, q0.y); s0q.y = cvtpk(q0.z, q0.w);
            s0q.z = cvtpk(q1.x, q1.y); s0q.w = cvtpk(q1.z, q1.w);
            s1q.x = cvtpk(q2.x, q2.y); s1q.y = cvtpk(q2.z, q2.w);
            s1q.z = cvtpk(q3.x, q3.y); s1q.w = cvtpk(q3.z, q3.w);
            s2q.x = cvtpk(q4.x, q4.y); s2q.y = cvtpk(q4.z, q4.w);
            s2q.z = cvtpk(q5.x, q5.y); s2q.w = cvtpk(q5.z, q5.w);
            s3q.x = cvtpk(q6.x, q6.y); s3q.y = cvtpk(q6.z, q6.w);
            s3q.z = cvtpk(q7.x, q7.y); s3q.w = cvtpk(q7.z, q7.w);
            uint4* hv = (uint4*)hb;
            hv[0] = s0q; hv[1] = s1q; hv[2] = s2q; hv[3] = s3q;
        }
    }

    // ---- non-identity fallback (one serial wave per dir, block g==0) ----
    if (!iF && g == 0 && wv == 0)
        rnn_serial_f<0>(Wf, bihf, bhhf, Whf, x, hbuf, b, lane, hshd[0]);
    if (!iB && g == 0 && wv == 1)
        rnn_serial_f<1>(Wb, bihb, bhhb, Whb, x, hbuf, b, lane, hshd[1]);
}

// ---------------- mlp: R12 exact (coalesced w0 + cvt_pk) --------------------
__global__ __launch_bounds__(256) void mlp_kernel(
    const unsigned short* __restrict__ hbuf,
    const float* __restrict__ w0, const float* __restrict__ b0,
    const float* __restrict__ w1, const float* __restrict__ b1,
    float* __restrict__ out)
{
    const int tid  = threadIdx.x;
    const int lane = tid & 63;
    const int wv   = tid >> 6;            // 0..3
    const int blk  = blockIdx.x;          // 0..4095
    const int b    = blk >> 5;
    const int t0   = (blk & 31) << 6;     // 64 t per block

    __shared__ __align__(16) unsigned int w0dw[128 * 64];   // 32 KB
    __shared__ __align__(16) unsigned int hsh[128 * 32];    // 16 KB

    // ---- stage w0: dense coalesced f4 loads, swizzled-linear LDS image ----
    #pragma unroll
    for (int it = 0; it < 16; ++it) {
        const int q = it * 256 + tid;         // f4 index 0..4095 (dense)
        const float4 v = ((const float4*)w0)[q];
        uint2 p;
        p.x = cvtpk(v.x, v.y);
        p.y = cvtpk(v.z, v.w);
        const int k  = q >> 5;                // k row 0..127
        const int dw = (k << 6) + ((q & 31) << 1);
        *(uint2*)(w0dw + (dw ^ ((k & 15) << 2))) = p;
    }

    // ---- stage h tile: 4 coalesced uint4 per thread ----
    #pragma unroll
    for (int it = 0; it < 4; ++it) {
        const int q   = it * 256 + tid;
        const int j   = q >> 3, sub = q & 7;
        const unsigned short* rp =
            hbuf + ((size_t)((j >> 6) * BB + b) * HH + (j & 63)) * TT + t0;
        const uint4 v = *(const uint4*)(rp + sub * 8);
        const int dwb = j * 32 + sub * 4;
        *(uint4*)(hsh + (dwb ^ (((j >> 3) & 3) << 3))) = v;
    }
    __syncthreads();

    const int lg = lane >> 4;                      // k-group 0..3
    const int tl = (wv << 4) + (lane & 15);        // t within tile
    const int t  = t0 + tl;                        // output column
    const int m  = lane & 15;

    f32x4 acc[8];
    #pragma unroll
    for (int kt = 0; kt < 8; ++kt) {
        const float4 v = *(const float4*)(b0 + kt * 16 + lg * 4);
        acc[kt][0] = v.x; acc[kt][1] = v.y; acc[kt][2] = v.z; acc[kt][3] = v.w;
    }

    const unsigned short* hus = (const unsigned short*)hsh;
    #pragma unroll
    for (int jt = 0; jt < 4; ++jt) {
        bf16x8 bf;
        #pragma unroll
        for (int i = 0; i < 8; ++i) {
            const int j  = jt * 32 + lg * 8 + i;
            const int dw = (j * 32 + (tl >> 1)) ^ (lg << 3);
            bf[i] = (short)hus[dw * 2 + (tl & 1)];
        }
        #pragma unroll
        for (int kt = 0; kt < 8; ++kt) {
            const int krow = kt * 16 + m;
            const bf16x8 af = *(const bf16x8*)(w0dw +
                ((((krow << 6) + (jt << 4) + (lg << 2)) ^ ((krow & 15) << 2))));
            acc[kt] = __builtin_amdgcn_mfma_f32_16x16x32_bf16(af, bf, acc[kt], 0, 0, 0);
        }
    }

    float o = 0.0f;
    #pragma unroll
    for (int kt = 0; kt < 8; ++kt) {
        const float4 wq = *(const float4*)(w1 + kt * 16 + lg * 4);
        float v0 = acc[kt][0]; v0 = fmaxf(v0, 0.01f * v0); o = fmaf(v0, wq.x, o);
        float v1 = acc[kt][1]; v1 = fmaxf(v1, 0.01f * v1); o = fmaf(v1, wq.y, o);
        float v2 = acc[kt][2]; v2 = fmaxf(v2, 0.01f * v2); o = fmaf(v2, wq.z, o);
        float v3 = acc[kt][3]; v3 = fmaxf(v3, 0.01f * v3); o = fmaf(v3, wq.w, o);
    }
    o += __shfl_xor(o, 16);
    o += __shfl_xor(o, 32);
    if (lg == 0) out[(size_t)b * TT + t] = o + b1[0];
}

extern "C" void kernel_launch(void* const* d_in, const int* in_sizes, int n_in,
                              void* d_out, int out_size, void* d_ws, size_t ws_size,
                              hipStream_t stream) {
    (void)in_sizes; (void)n_in; (void)out_size; (void)ws_size;
    const float* x    = (const float*)d_in[0];
    const float* Wihf = (const float*)d_in[1];
    const float* Whhf = (const float*)d_in[2];
    const float* bihf = (const float*)d_in[3];
    const float* bhhf = (const float*)d_in[4];
    const float* Wihb = (const float*)d_in[5];
    const float* Whhb = (const float*)d_in[6];
    const float* bihb = (const float*)d_in[7];
    const float* bhhb = (const float*)d_in[8];
    const float* ff0w = (const float*)d_in[9];
    const float* ff0b = (const float*)d_in[10];
    const float* ff1w = (const float*)d_in[11];
    const float* ff1b = (const float*)d_in[12];
    unsigned short* hbuf = (unsigned short*)d_ws;   // [2][BB][HH][TT] bf16, 67 MB

    rnn_fused_kernel<<<dim3(16 * BB), dim3(512), 0, stream>>>(
        x, Wihf, bihf, bhhf, Wihb, bihb, bhhb, Whhf, Whhb, hbuf);
    mlp_kernel<<<dim3(BB * (TT / 64)), dim3(256), 0, stream>>>(
        hbuf, ff0w, ff0b, ff1w, ff1b, (float*)d_out);
}